// Round 2
// baseline (16858.363 us; speedup 1.0000x reference)
//
#include <hip/hip_runtime.h>
#include <hip/hip_bf16.h>
#include <math.h>

#define SEQ 512
#define NB  64
#define NIN 512
#define NH  1024
#define NO  512

typedef __bf16 bf16x8 __attribute__((ext_vector_type(8)));
typedef float  f32x4  __attribute__((ext_vector_type(4)));

__device__ __forceinline__ f32x4 mfma16(bf16x8 a, bf16x8 b, f32x4 c) {
  return __builtin_amdgcn_mfma_f32_16x16x32_bf16(a, b, c, 0, 0, 0);
}

// Persistent RNN kernel.
// Grid: 256 WGs = 4 groups (16 batches each) x 64 WGs (16-col j-slice of H).
// Each WG: 256 threads = 4 waves, K split 4 ways:
//   wave wv: H-k in [wv*256, wv*256+256), IN-k in [wv*128, wv*128+128).
// Weights live in registers as bf16 hi/lo fragments (~128 VGPR/thread).
// h state exchanged via global double buffer (bf16 hi+lo planes) + per-WG
// flags with device-scope release/acquire. Only co-residency is required
// (capacity >= 2 blocks/CU at 256 VGPR cap), so a plain launch is a safe
// fallback if cooperative launch is rejected.
__global__ __launch_bounds__(256, 2)
void rnn_persistent(const float* __restrict__ x, const float* __restrict__ h0,
                    const float* __restrict__ i_h, const float* __restrict__ h_h,
                    const float* __restrict__ h_o, const float* __restrict__ b_i,
                    const float* __restrict__ b_o, float* __restrict__ out,
                    int* __restrict__ flags, __bf16* __restrict__ hbuf) {
  const int bid  = blockIdx.x;
  const int g    = bid & 3;          // group id (batch slice)
  const int w    = bid >> 2;         // 0..63  (hidden-column slice)
  const int wv   = threadIdx.x >> 6; // wave 0..3
  const int lane = threadIdx.x & 63;
  const int tn   = lane & 15;        // A-row (batch) / C-col index
  const int tq   = lane >> 4;        // k-subblock / C-row-block index
  const int Bg   = g * 16;
  const int Jw   = w * 16;
  const int Ow   = w * 8;
  const int kb0  = wv * 256;         // this wave's H-k base
  const int xb0  = wv * 128;         // this wave's IN-k base

  __shared__ float red_h[3 * 256];   // waves 1..3 partial acc_h
  __shared__ float red_o[3 * 256];   // waves 1..3 partial acc_o

  // ---- invariant weight fragments in registers (bf16 hi/lo split) ----
  bf16x8 whi[8], wlo[8], hof[8], ihhi[4], ihlo[4];
#pragma unroll
  for (int c = 0; c < 8; ++c) {
    const int kb = kb0 + c * 32 + tq * 8;
#pragma unroll
    for (int j = 0; j < 8; ++j) {
      float v = h_h[(kb + j) * NH + Jw + tn];
      __bf16 hi = (__bf16)v;
      whi[c][j] = hi;
      wlo[c][j] = (__bf16)(v - (float)hi);
      float vo = (tn < 8) ? h_o[(kb + j) * NO + Ow + tn] : 0.0f;
      hof[c][j] = (__bf16)vo;
    }
  }
#pragma unroll
  for (int c = 0; c < 4; ++c) {
    const int kb = xb0 + c * 32 + tq * 8;
#pragma unroll
    for (int j = 0; j < 8; ++j) {
      float v = i_h[(kb + j) * NH + Jw + tn];
      __bf16 hi = (__bf16)v;
      ihhi[c][j] = hi;
      ihlo[c][j] = (__bf16)(v - (float)hi);
    }
  }
  const float bi = b_i[Jw + tn];
  const float bo = (tn < 8) ? b_o[Ow + tn] : 0.0f;

  int* fl = flags + g * 64;
  __bf16* hb = hbuf;   // layout: [parity][hi/lo][64 rows][1024 cols] bf16

  // ---- init: wave 0 publishes h0 slice into parity-0 buffer ----
  if (wv == 0) {
#pragma unroll
    for (int r = 0; r < 4; ++r) {
      const int row = Bg + tq * 4 + r;
      float v = h0[row * NH + Jw + tn];
      __bf16 hi = (__bf16)v;
      hb[row * NH + Jw + tn] = hi;
      hb[65536 + row * NH + Jw + tn] = (__bf16)(v - (float)hi);
    }
    __threadfence();
    if (lane == 0)
      __hip_atomic_store(&fl[w], 1, __ATOMIC_RELAXED, __HIP_MEMORY_SCOPE_AGENT);
  }

  for (int t = 0; t < SEQ; ++t) {
    // ---- wait until h_state[t] fully published by this group ----
    const int tgt = t + 1;
    while (true) {
      int v = __hip_atomic_load(&fl[lane], __ATOMIC_RELAXED, __HIP_MEMORY_SCOPE_AGENT);
      if (__all(v >= tgt)) break;
    }
    __threadfence();  // acquire: make hbuf writes visible

    const __bf16* hhi = hb + (t & 1) * 131072;
    const __bf16* hlo = hhi + 65536;

    f32x4 acc_h = {0.f, 0.f, 0.f, 0.f};
    f32x4 acc_o = {0.f, 0.f, 0.f, 0.f};

    // h-mix (this wave's K quarter) + fused output projection of o_{t-1}
#pragma unroll
    for (int c = 0; c < 8; ++c) {
      const int k = kb0 + c * 32 + tq * 8;
      bf16x8 ahi = *(const bf16x8*)(hhi + (Bg + tn) * NH + k);
      bf16x8 alo = *(const bf16x8*)(hlo + (Bg + tn) * NH + k);
      acc_h = mfma16(ahi, whi[c], acc_h);
      acc_h = mfma16(alo, whi[c], acc_h);
      acc_h = mfma16(ahi, wlo[c], acc_h);
      acc_o = mfma16(ahi, hof[c], acc_o);
      acc_o = mfma16(alo, hof[c], acc_o);
    }
    // xi contribution (x consumed on the fly; hi/lo split of x)
#pragma unroll
    for (int c = 0; c < 4; ++c) {
      const int k = xb0 + c * 32 + tq * 8;
      const float* xp = x + (size_t)(t * NB + Bg + tn) * NIN + k;
      f32x4 xa = *(const f32x4*)xp;
      f32x4 xb2 = *(const f32x4*)(xp + 4);
      bf16x8 xhi, xlo;
#pragma unroll
      for (int e = 0; e < 4; ++e) {
        __bf16 h1 = (__bf16)xa[e];
        xhi[e] = h1; xlo[e] = (__bf16)(xa[e] - (float)h1);
        __bf16 h2 = (__bf16)xb2[e];
        xhi[4 + e] = h2; xlo[4 + e] = (__bf16)(xb2[e] - (float)h2);
      }
      acc_h = mfma16(xhi, ihhi[c], acc_h);
      acc_h = mfma16(xlo, ihhi[c], acc_h);
      acc_h = mfma16(xhi, ihlo[c], acc_h);
    }

    // ---- combine the 4 waves' K-partials ----
    if (wv > 0) {
      const int base = (wv - 1) * 256 + lane * 4;
#pragma unroll
      for (int r = 0; r < 4; ++r) {
        red_h[base + r] = acc_h[r];
        red_o[base + r] = acc_o[r];
      }
    }
    __syncthreads();
    if (wv == 0) {
#pragma unroll
      for (int p = 0; p < 3; ++p) {
        const int base = p * 256 + lane * 4;
#pragma unroll
        for (int r = 0; r < 4; ++r) {
          acc_h[r] += red_h[base + r];
          acc_o[r] += red_o[base + r];
        }
      }

      __bf16* nhi = hb + ((t + 1) & 1) * 131072;
      __bf16* nlo = nhi + 65536;
      float hv[4];
#pragma unroll
      for (int r = 0; r < 4; ++r) {
        const int row = Bg + tq * 4 + r;
        float v = tanhf(acc_h[r] + bi);
        hv[r] = v;
        __bf16 hi = (__bf16)v;
        nhi[row * NH + Jw + tn] = hi;
        nlo[row * NH + Jw + tn] = (__bf16)(v - (float)hi);
      }
      __threadfence();  // release hbuf writes
      if (lane == 0)
        __hip_atomic_store(&fl[w], t + 2, __ATOMIC_RELAXED, __HIP_MEMORY_SCOPE_AGENT);

      if (t == SEQ - 1) {
        // h_final (fp32) tail of d_out
#pragma unroll
        for (int r = 0; r < 4; ++r) {
          const int row = Bg + tq * 4 + r;
          out[(size_t)SEQ * NB * NO + row * NH + Jw + tn] = hv[r];
        }
      }
      // o_{t-1} = leaky_relu(h_state[t] @ h_o + b_o)  (off critical path)
      if (t >= 1 && tn < 8) {
#pragma unroll
        for (int r = 0; r < 4; ++r) {
          const int row = Bg + tq * 4 + r;
          float o = acc_o[r] + bo;
          o = (o >= 0.f) ? o : 0.01f * o;
          out[((size_t)(t - 1) * NB + row) * NO + Ow + tn] = o;
        }
      }
    }
  }

  // ---- epilogue: o_{SEQ-1} from h_state[SEQ] ----
  {
    const int tgt = SEQ + 1;
    while (true) {
      int v = __hip_atomic_load(&fl[lane], __ATOMIC_RELAXED, __HIP_MEMORY_SCOPE_AGENT);
      if (__all(v >= tgt)) break;
    }
    __threadfence();
    const __bf16* hhi = hb + (SEQ & 1) * 131072;
    const __bf16* hlo = hhi + 65536;
    f32x4 acc_o = {0.f, 0.f, 0.f, 0.f};
#pragma unroll
    for (int c = 0; c < 8; ++c) {
      const int k = kb0 + c * 32 + tq * 8;
      bf16x8 ahi = *(const bf16x8*)(hhi + (Bg + tn) * NH + k);
      bf16x8 alo = *(const bf16x8*)(hlo + (Bg + tn) * NH + k);
      acc_o = mfma16(ahi, hof[c], acc_o);
      acc_o = mfma16(alo, hof[c], acc_o);
    }
    if (wv > 0) {
      const int base = (wv - 1) * 256 + lane * 4;
#pragma unroll
      for (int r = 0; r < 4; ++r) red_o[base + r] = acc_o[r];
    }
    __syncthreads();
    if (wv == 0 && tn < 8) {
#pragma unroll
      for (int r = 0; r < 4; ++r) {
        float s = acc_o[r];
#pragma unroll
        for (int p = 0; p < 3; ++p) s += red_o[p * 256 + lane * 4 + r];
        const int row = Bg + tq * 4 + r;
        float o = s + bo;
        o = (o >= 0.f) ? o : 0.01f * o;
        out[((size_t)(SEQ - 1) * NB + row) * NO + Ow + tn] = o;
      }
    }
  }
}

extern "C" void kernel_launch(void* const* d_in, const int* in_sizes, int n_in,
                              void* d_out, int out_size, void* d_ws, size_t ws_size,
                              hipStream_t stream) {
  (void)in_sizes; (void)n_in; (void)out_size; (void)ws_size;
  const float* x   = (const float*)d_in[0];
  const float* h0  = (const float*)d_in[1];
  const float* i_h = (const float*)d_in[2];
  const float* h_h = (const float*)d_in[3];
  const float* h_o = (const float*)d_in[4];
  const float* b_i = (const float*)d_in[5];
  const float* b_o = (const float*)d_in[6];
  float* out = (float*)d_out;
  int* flags = (int*)d_ws;                       // 256 ints
  __bf16* hbuf = (__bf16*)((char*)d_ws + 4096);  // 512 KB double buffer

  hipMemsetAsync(d_ws, 0, 1024, stream);

  void* args[] = {&x, &h0, &i_h, &h_h, &h_o, &b_i, &b_o, &out, &flags, &hbuf};
  hipError_t err = hipLaunchCooperativeKernel((const void*)rnn_persistent,
                                              dim3(256), dim3(256), args, 0, stream);
  if (err != hipSuccess) {
    // Plain launch fallback: protocol only needs co-residency, and capacity
    // (>=2 blocks/CU at the 256-VGPR cap, 6KB LDS) is >= 2x the grid.
    rnn_persistent<<<dim3(256), dim3(256), 0, stream>>>(
        x, h0, i_h, h_h, h_o, b_i, b_o, out, flags, hbuf);
  }
}

// Round 3
// 3378.660 us; speedup vs baseline: 4.9897x; 4.9897x over previous
//
#include <hip/hip_runtime.h>
#include <hip/hip_bf16.h>
#include <math.h>

#define SEQ 512
#define NB  64
#define NIN 512
#define NH  1024
#define NO  512

typedef __bf16 bf16x8 __attribute__((ext_vector_type(8)));
typedef float  f32x4  __attribute__((ext_vector_type(4)));

__device__ __forceinline__ f32x4 mfma16(bf16x8 a, bf16x8 b, f32x4 c) {
  return __builtin_amdgcn_mfma_f32_16x16x32_bf16(a, b, c, 0, 0, 0);
}

// Persistent RNN kernel, IF-cache-coherent exchange (no L2 fences).
// Grid: 256 WGs = 4 groups (16 batches) x 64 WGs (16-col j-slice of H).
// Each WG: 256 threads = 4 waves, K split 4 ways.
// Weights in registers as bf16 hi/lo fragments.
// h state exchanged as fp32 through a double buffer using agent-scope
// relaxed atomics (sc0+sc1: write-through to Infinity Cache, loads bypass
// stale L1/L2) — the coherence point is IF, so NO buffer_wbl2/buffer_inv
// fences are needed. Release ordering = s_waitcnt vmcnt(0) + relaxed flag.
__global__ __launch_bounds__(256, 2)
void rnn_persistent(const float* __restrict__ x, const float* __restrict__ h0,
                    const float* __restrict__ i_h, const float* __restrict__ h_h,
                    const float* __restrict__ h_o, const float* __restrict__ b_i,
                    const float* __restrict__ b_o, float* __restrict__ out,
                    int* __restrict__ flags, float* __restrict__ hbuf) {
  const int bid  = blockIdx.x;
  const int g    = bid & 3;          // group id (batch slice)
  const int w    = bid >> 2;         // 0..63  (hidden-column slice)
  const int wv   = threadIdx.x >> 6; // wave 0..3
  const int lane = threadIdx.x & 63;
  const int tn   = lane & 15;        // A-row (batch) / C-col index
  const int tq   = lane >> 4;        // k-subblock / C-row-block index
  const int Bg   = g * 16;
  const int Jw   = w * 16;
  const int Ow   = w * 8;
  const int kb0  = wv * 256;         // this wave's H-k base
  const int xb0  = wv * 128;         // this wave's IN-k base

  __shared__ float red_h[3 * 256];   // waves 1..3 partial acc_h
  __shared__ float red_o[3 * 256];   // waves 1..3 partial acc_o

  // ---- invariant weight fragments in registers (bf16 hi/lo split) ----
  bf16x8 whi[8], wlo[8], hof[8], ihhi[4], ihlo[4];
#pragma unroll
  for (int c = 0; c < 8; ++c) {
    const int kb = kb0 + c * 32 + tq * 8;
#pragma unroll
    for (int j = 0; j < 8; ++j) {
      float v = h_h[(kb + j) * NH + Jw + tn];
      __bf16 hi = (__bf16)v;
      whi[c][j] = hi;
      wlo[c][j] = (__bf16)(v - (float)hi);
      float vo = (tn < 8) ? h_o[(kb + j) * NO + Ow + tn] : 0.0f;
      hof[c][j] = (__bf16)vo;
    }
  }
#pragma unroll
  for (int c = 0; c < 4; ++c) {
    const int kb = xb0 + c * 32 + tq * 8;
#pragma unroll
    for (int j = 0; j < 8; ++j) {
      float v = i_h[(kb + j) * NH + Jw + tn];
      __bf16 hi = (__bf16)v;
      ihhi[c][j] = hi;
      ihlo[c][j] = (__bf16)(v - (float)hi);
    }
  }
  const float bi = b_i[Jw + tn];
  const float bo = (tn < 8) ? b_o[Ow + tn] : 0.0f;

  int* fl = flags + g * 64;
  float* hb = hbuf;   // layout: [parity][64 rows][1024 cols] fp32

  // ---- init: wave 0 publishes h0 slice into parity-0 buffer ----
  if (wv == 0) {
#pragma unroll
    for (int r = 0; r < 4; ++r) {
      const int row = Bg + tq * 4 + r;
      __hip_atomic_store(&hb[row * NH + Jw + tn], h0[row * NH + Jw + tn],
                         __ATOMIC_RELAXED, __HIP_MEMORY_SCOPE_AGENT);
    }
    asm volatile("s_waitcnt vmcnt(0)" ::: "memory");
    if (lane == 0)
      __hip_atomic_store(&fl[w], 1, __ATOMIC_RELAXED, __HIP_MEMORY_SCOPE_AGENT);
  }

  for (int t = 0; t < SEQ; ++t) {
    f32x4 acc_h = {0.f, 0.f, 0.f, 0.f};
    f32x4 acc_o = {0.f, 0.f, 0.f, 0.f};

    // ---- xi contribution first: independent of h_t, overlaps others' work
#pragma unroll
    for (int c = 0; c < 4; ++c) {
      const int k = xb0 + c * 32 + tq * 8;
      const float* xp = x + (size_t)(t * NB + Bg + tn) * NIN + k;
      f32x4 xa = *(const f32x4*)xp;
      f32x4 xb2 = *(const f32x4*)(xp + 4);
      bf16x8 xhi, xlo;
#pragma unroll
      for (int e = 0; e < 4; ++e) {
        __bf16 h1 = (__bf16)xa[e];
        xhi[e] = h1; xlo[e] = (__bf16)(xa[e] - (float)h1);
        __bf16 h2 = (__bf16)xb2[e];
        xhi[4 + e] = h2; xlo[4 + e] = (__bf16)(xb2[e] - (float)h2);
      }
      acc_h = mfma16(xhi, ihhi[c], acc_h);
      acc_h = mfma16(xlo, ihhi[c], acc_h);
      acc_h = mfma16(xhi, ihlo[c], acc_h);
    }

    // ---- wait until h_state[t] fully published (wave 0 spins) ----
    if (wv == 0) {
      const int tgt = t + 1;
      while (true) {
        int v = __hip_atomic_load(&fl[lane], __ATOMIC_RELAXED, __HIP_MEMORY_SCOPE_AGENT);
        if (__all(v >= tgt)) break;
      }
    }
    __syncthreads();

    // ---- h-mix + fused output projection, reading fresh fp32 h from IF ----
    const float* hP = hb + (t & 1) * 65536;
#pragma unroll
    for (int c = 0; c < 8; ++c) {
      const int k = kb0 + c * 32 + tq * 8;
      const float* rowp = hP + (Bg + tn) * NH + k;
      unsigned long long q[4];
#pragma unroll
      for (int u = 0; u < 4; ++u)
        q[u] = __hip_atomic_load((const unsigned long long*)rowp + u,
                                 __ATOMIC_RELAXED, __HIP_MEMORY_SCOPE_AGENT);
      bf16x8 ahi, alo;
#pragma unroll
      for (int u = 0; u < 4; ++u) {
        float f0 = __builtin_bit_cast(float, (unsigned)(q[u] & 0xffffffffull));
        float f1 = __builtin_bit_cast(float, (unsigned)(q[u] >> 32));
        __bf16 b0 = (__bf16)f0;
        ahi[2 * u] = b0; alo[2 * u] = (__bf16)(f0 - (float)b0);
        __bf16 b1 = (__bf16)f1;
        ahi[2 * u + 1] = b1; alo[2 * u + 1] = (__bf16)(f1 - (float)b1);
      }
      acc_h = mfma16(ahi, whi[c], acc_h);
      acc_h = mfma16(alo, whi[c], acc_h);
      acc_h = mfma16(ahi, wlo[c], acc_h);
      acc_o = mfma16(ahi, hof[c], acc_o);
      acc_o = mfma16(alo, hof[c], acc_o);
    }

    // ---- combine the 4 waves' K-partials ----
    if (wv > 0) {
      const int base = (wv - 1) * 256 + lane * 4;
#pragma unroll
      for (int r = 0; r < 4; ++r) {
        red_h[base + r] = acc_h[r];
        red_o[base + r] = acc_o[r];
      }
    }
    __syncthreads();
    if (wv == 0) {
      // critical path first: reduce h, tanh, publish, flag
#pragma unroll
      for (int p = 0; p < 3; ++p) {
        const int base = p * 256 + lane * 4;
#pragma unroll
        for (int r = 0; r < 4; ++r) acc_h[r] += red_h[base + r];
      }
      float* nP = hb + ((t + 1) & 1) * 65536;
      float hv[4];
#pragma unroll
      for (int r = 0; r < 4; ++r) {
        const int row = Bg + tq * 4 + r;
        float v = tanhf(acc_h[r] + bi);
        hv[r] = v;
        __hip_atomic_store(&nP[row * NH + Jw + tn], v,
                           __ATOMIC_RELAXED, __HIP_MEMORY_SCOPE_AGENT);
      }
      asm volatile("s_waitcnt vmcnt(0)" ::: "memory");
      if (lane == 0)
        __hip_atomic_store(&fl[w], t + 2, __ATOMIC_RELAXED, __HIP_MEMORY_SCOPE_AGENT);

      // off critical path: o_{t-1} and h_final
#pragma unroll
      for (int p = 0; p < 3; ++p) {
        const int base = p * 256 + lane * 4;
#pragma unroll
        for (int r = 0; r < 4; ++r) acc_o[r] += red_o[base + r];
      }
      if (t >= 1 && tn < 8) {
#pragma unroll
        for (int r = 0; r < 4; ++r) {
          const int row = Bg + tq * 4 + r;
          float o = acc_o[r] + bo;
          o = (o >= 0.f) ? o : 0.01f * o;
          out[((size_t)(t - 1) * NB + row) * NO + Ow + tn] = o;
        }
      }
      if (t == SEQ - 1) {
#pragma unroll
        for (int r = 0; r < 4; ++r) {
          const int row = Bg + tq * 4 + r;
          out[(size_t)SEQ * NB * NO + row * NH + Jw + tn] = hv[r];
        }
      }
    }
  }

  // ---- epilogue: o_{SEQ-1} from h_state[SEQ] (parity SEQ&1 == 0) ----
  {
    if (wv == 0) {
      const int tgt = SEQ + 1;
      while (true) {
        int v = __hip_atomic_load(&fl[lane], __ATOMIC_RELAXED, __HIP_MEMORY_SCOPE_AGENT);
        if (__all(v >= tgt)) break;
      }
    }
    __syncthreads();
    const float* hP = hb + (SEQ & 1) * 65536;
    f32x4 acc_o = {0.f, 0.f, 0.f, 0.f};
#pragma unroll
    for (int c = 0; c < 8; ++c) {
      const int k = kb0 + c * 32 + tq * 8;
      const float* rowp = hP + (Bg + tn) * NH + k;
      unsigned long long q[4];
#pragma unroll
      for (int u = 0; u < 4; ++u)
        q[u] = __hip_atomic_load((const unsigned long long*)rowp + u,
                                 __ATOMIC_RELAXED, __HIP_MEMORY_SCOPE_AGENT);
      bf16x8 ahi, alo;
#pragma unroll
      for (int u = 0; u < 4; ++u) {
        float f0 = __builtin_bit_cast(float, (unsigned)(q[u] & 0xffffffffull));
        float f1 = __builtin_bit_cast(float, (unsigned)(q[u] >> 32));
        __bf16 b0 = (__bf16)f0;
        ahi[2 * u] = b0; alo[2 * u] = (__bf16)(f0 - (float)b0);
        __bf16 b1 = (__bf16)f1;
        ahi[2 * u + 1] = b1; alo[2 * u + 1] = (__bf16)(f1 - (float)b1);
      }
      acc_o = mfma16(ahi, hof[c], acc_o);
      acc_o = mfma16(alo, hof[c], acc_o);
    }
    if (wv > 0) {
      const int base = (wv - 1) * 256 + lane * 4;
#pragma unroll
      for (int r = 0; r < 4; ++r) red_o[base + r] = acc_o[r];
    }
    __syncthreads();
    if (wv == 0 && tn < 8) {
#pragma unroll
      for (int r = 0; r < 4; ++r) {
        float s = acc_o[r];
#pragma unroll
        for (int p = 0; p < 3; ++p) s += red_o[p * 256 + lane * 4 + r];
        const int row = Bg + tq * 4 + r;
        float o = s + bo;
        o = (o >= 0.f) ? o : 0.01f * o;
        out[((size_t)(SEQ - 1) * NB + row) * NO + Ow + tn] = o;
      }
    }
  }
}

extern "C" void kernel_launch(void* const* d_in, const int* in_sizes, int n_in,
                              void* d_out, int out_size, void* d_ws, size_t ws_size,
                              hipStream_t stream) {
  (void)in_sizes; (void)n_in; (void)out_size; (void)ws_size;
  const float* x   = (const float*)d_in[0];
  const float* h0  = (const float*)d_in[1];
  const float* i_h = (const float*)d_in[2];
  const float* h_h = (const float*)d_in[3];
  const float* h_o = (const float*)d_in[4];
  const float* b_i = (const float*)d_in[5];
  const float* b_o = (const float*)d_in[6];
  float* out = (float*)d_out;
  int* flags = (int*)d_ws;                       // 256 ints
  float* hbuf = (float*)((char*)d_ws + 4096);    // 2 x 64 x 1024 fp32 = 512 KB

  hipMemsetAsync(d_ws, 0, 1024, stream);

  void* args[] = {&x, &h0, &i_h, &h_h, &h_o, &b_i, &b_o, &out, &flags, &hbuf};
  hipError_t err = hipLaunchCooperativeKernel((const void*)rnn_persistent,
                                              dim3(256), dim3(256), args, 0, stream);
  if (err != hipSuccess) {
    // Plain launch fallback: protocol only needs co-residency (grid 256 =
    // 1 block/CU at this footprint).
    rnn_persistent<<<dim3(256), dim3(256), 0, stream>>>(
        x, h0, i_h, h_h, h_o, b_i, b_o, out, flags, hbuf);
  }
}